// Round 17
// baseline (218.138 us; speedup 1.0000x reference)
//
#include <hip/hip_runtime.h>
#include <stdint.h>

#define BATCH 8
#define NPRI 100000
#define NGT 16
#define NCLS 41
#define F_POS_TH 0.5f
#define F_NEG_TH 0.4f

// k_conf geometry: 4-wave blocks, each wave owns a 64-row tile, register streaming
static constexpr int TILES_PER_B = (NPRI + 63) / 64;  // 1563
static constexpr int CBLK = (TILES_PER_B + 3) / 4;    // 391 blocks per batch
static constexpr int CW = 64 * NCLS / 4;              // 656 f32x4 chunks per tile
static constexpr int H0BIN = 256;                     // lvl0 hist bins (key top-8 bits)
static constexpr int NBIN = 4096;                     // k_select lvl1/2 bins

// ---- workspace layout (bytes) ----
static constexpr size_t OFF_KEY  = 0;                               // u32 [B*P] lc bits
static constexpr size_t OFF_GTC  = OFF_KEY + (size_t)BATCH*NPRI*4;  // u64 [B*16]
static constexpr size_t OFF_HG   = OFF_GTC + BATCH*NGT*8;           // u32 [B][256] lvl0 hist
static constexpr size_t OFF_NPOS = OFF_HG + (size_t)BATCH*H0BIN*4;  // u32 [B]
static constexpr size_t OFF_SL1  = OFF_NPOS + BATCH*4;              // f32 [B]
static constexpr size_t OFF_CEP  = OFF_SL1  + BATCH*4;              // f32 [B]
static constexpr size_t OFF_NEG  = OFF_CEP  + BATCH*4;              // f32 [B]
static constexpr size_t OFF_FTK  = OFF_NEG  + BATCH*4;              // u32 [1]
static constexpr int ZERO_U32 = (int)((OFF_FTK + 4 - OFF_HG) / 4);  // hist + scalars

typedef float f32x4 __attribute__((ext_vector_type(4)));

__device__ inline float smoothl1(float d) {
  float a = fabsf(d);
  return a < 1.f ? 0.5f * d * d : a - 0.5f;
}
__device__ inline float sl1_terms(f32x4 pv, f32x4 ld, f32x4 gv) {
  float tx = ((gv[0] + gv[2]) * 0.5f - pv[0]) / (0.1f * pv[2]);
  float ty = ((gv[1] + gv[3]) * 0.5f - pv[1]) / (0.1f * pv[3]);
  float tw = __logf(fmaxf((gv[2] - gv[0]) / pv[2], 1e-8f)) / 0.2f;
  float th = __logf(fmaxf((gv[3] - gv[1]) / pv[3], 1e-8f)) / 0.2f;
  return smoothl1(ld[0] - tx) + smoothl1(ld[1] - ty)
       + smoothl1(ld[2] - tw) + smoothl1(ld[3] - th);
}
__device__ inline float aload_f32(const float* p) {
  return __hip_atomic_load(p, __ATOMIC_RELAXED, __HIP_MEMORY_SCOPE_AGENT);
}
__device__ inline unsigned aload_u32(const unsigned* p) {
  return __hip_atomic_load(p, __ATOMIC_RELAXED, __HIP_MEMORY_SCOPE_AGENT);
}

// ---------------- K_init: zero hist+scalars, gtc baseline ----------------
// gtc re-based every call: ws poison 0xAA.. would win atomicMax otherwise.
__global__ void k_init(unsigned* __restrict__ z, unsigned long long* __restrict__ gtc) {
  int t = threadIdx.x;  // 512 threads
  for (int i = t; i < ZERO_U32; i += 512) z[i] = 0u;
  if (t < BATCH * NGT) gtc[t] = 0xFFFFFFFFull;  // (iou=0)<<32 | (0xFFFFFFFF - p=0)
}

// ---------------- K_conf: register-streaming, tiny LDS, max occupancy ----------------
// Each wave owns a 64-row tile; chunks stream through a 2-deep named-register
// rotation (cA/cB, compile-time indices -> no array sink, compiler free to
// pipeline deeper). LDS = per-wave sums/r0s slices + block hist/best: ~3.3 KB
// -> up to 8 blocks (32 waves)/CU. Per-gt argmax fused (no k_match kernel);
// force-match applied in k_select's prologue.
__global__ __launch_bounds__(256) void k_conf(
    const float* __restrict__ loc, const float* __restrict__ conf,
    const float* __restrict__ priors, const float* __restrict__ gtb,
    const int* __restrict__ gtl,
    unsigned* __restrict__ key, unsigned* __restrict__ histg,
    unsigned long long* __restrict__ gtc,
    unsigned* __restrict__ npos, float* __restrict__ sl1sum, float* __restrict__ cepos) {
  __shared__ float sums[4][64];
  __shared__ float r0s[4][64];
  __shared__ unsigned hcb[H0BIN];
  __shared__ unsigned long long best[NGT];
  __shared__ float redS[4], redC[4]; __shared__ unsigned redP[4];
  const int t = threadIdx.x, w = t >> 6, l = t & 63;
  const int b = blockIdx.y;
  const int tile = blockIdx.x * 4 + w;
  hcb[t] = 0u;           // t < 256 == H0BIN
  if (t < NGT) best[t] = 0;
  sums[w][l] = 0.f;      // own-wave slice
  __syncthreads();       // hcb/best zeroing visible to all waves
  float accS = 0.f, accC = 0.f; unsigned accP = 0;
  if (tile < TILES_PER_B) {
    const f32x4* c4b = (const f32x4*)conf + (size_t)b * (NPRI * NCLS / 4);
    const unsigned bend = (unsigned)(NPRI * NCLS / 4 - 1);
    const unsigned tbase = (unsigned)tile * CW;
    const int p = tile * 64 + l;
    const bool valid = p < NPRI;
    const int pc = valid ? p : NPRI - 1;
    const f32x4 pv = ((const f32x4*)priors)[pc];
    const f32x4 ld = ((const f32x4*)loc)[(size_t)b * NPRI + pc];
    // ---- stream 11 chunks through a 2-deep rotation; all loads unconditional ----
    f32x4 cA = c4b[min(tbase + (unsigned)l, bend)];
#pragma unroll
    for (int u = 0; u < 11; u++) {
      f32x4 cB;
      {  // next chunk (u+1), clamped both tile-locally and batch-globally
        unsigned cn = (unsigned)((u + 1) * 64 + l);
        cn = cn < (unsigned)CW ? cn : (unsigned)(CW - 1);
        cB = c4b[min(tbase + cn, bend)];
      }
      int cidx = u * 64 + l;
      if (cidx < CW) {           // compute predicated; loads were unconditional
        int f = cidx * 4;        // float offset within tile
        int r0 = (int)((unsigned)f / 41u);
        int rem = f - r0 * 41;
        float e0 = __expf(cA[0]);
        float e1 = __expf(cA[1]);
        float e2 = __expf(cA[2]);
        float e3 = __expf(cA[3]);
        int nlo = 41 - rem;      // elements belonging to row r0
        float slo = e0, shi = 0.f;
        if (nlo > 1) slo += e1; else shi += e1;
        if (nlo > 2) slo += e2; else shi += e2;
        if (nlo > 3) slo += e3; else shi += e3;
        atomicAdd(&sums[w][r0], slo);
        if (nlo <= 3) atomicAdd(&sums[w][r0 + 1], shi);  // never fires at r0==63
        if (rem == 0) r0s[w][r0] = cA[0];
        else if (nlo <= 3) {
          float v = (nlo == 1) ? cA[1] : (nlo == 2) ? cA[2] : cA[3];
          r0s[w][r0 + 1] = v;
        }
      }
      cA = cB;
    }
    // same-wave ds ops complete in program order: safe to read own slice
    float lse = __logf(sums[w][l]);
    float r0v = r0s[w][l];
    unsigned kkreg = 0u;
    if (valid) {
      // per-prior match + fused per-gt argmax
      float px1 = pv[0] - 0.5f * pv[2], py1 = pv[1] - 0.5f * pv[3];
      float px2 = pv[0] + 0.5f * pv[2], py2 = pv[1] + 0.5f * pv[3];
      float parea = (px2 - px1) * (py2 - py1);
      float bov = 0.f; int g = 0;
#pragma unroll
      for (int gg = 0; gg < NGT; gg++) {
        const f32x4 gv = ((const f32x4*)gtb)[b * NGT + gg];
        float ix = fmaxf(fminf(px2, gv[2]) - fmaxf(px1, gv[0]), 0.f);
        float iy = fmaxf(fminf(py2, gv[3]) - fmaxf(py1, gv[1]), 0.f);
        float inter = ix * iy;
        float garea = (gv[2] - gv[0]) * (gv[3] - gv[1]);
        float iou = inter / (parea + garea - inter);
        if (iou > bov) { bov = iou; g = gg; }
        if (iou > 0.f) {
          unsigned long long comp = ((unsigned long long)__float_as_uint(iou) << 32)
                                  | (unsigned long long)(0xFFFFFFFFu - (unsigned)p);
          if (comp > best[gg]) atomicMax(&best[gg], comp);
        }
      }
      int c = gtl[b * NGT + g];
      if (bov < F_POS_TH) c = -1;
      if (bov < F_NEG_TH) c = 0;
      kkreg = (c == 0) ? __float_as_uint(lse - r0v) : 0u;
      key[(size_t)b * NPRI + p] = kkreg;
      if (c > 0) {
        accP = 1;
        float rc = conf[((size_t)b * NPRI + p) * NCLS + c];  // rare scattered re-read
        accC = lse - rc;
        const f32x4 gvb = ((const f32x4*)gtb)[b * NGT + g];
        accS = sl1_terms(pv, ld, gvb);
      }
    }
    // lvl0 hist, hot bins (0x40 and 0) ballot-aggregated
    unsigned bin = kkreg >> 24;
    unsigned long long m40 = __ballot(valid && kkreg != 0u && bin == 0x40u);
    unsigned long long m00 = __ballot(valid && kkreg == 0u);
    if (m40 && l == __ffsll((long long)m40) - 1)
      atomicAdd(&hcb[0x40], (unsigned)__popcll(m40));
    if (m00 && l == __ffsll((long long)m00) - 1)
      atomicAdd(&hcb[0], (unsigned)__popcll(m00));
    if (valid && kkreg != 0u && bin != 0x40u) atomicAdd(&hcb[bin], 1u);
  }
  __syncthreads();  // hcb/best atomics visible block-wide
  if (t < NGT && best[t] != 0) atomicMax(&gtc[b * NGT + t], best[t]);
  { unsigned v = hcb[t]; if (v) atomicAdd(&histg[b * H0BIN + t], v); }
  // block reduction, one atomic set per block
  float vs = accS, vc = accC; unsigned vp = accP;
#pragma unroll
  for (int off = 32; off; off >>= 1) {
    vs += __shfl_down(vs, off, 64);
    vc += __shfl_down(vc, off, 64);
    vp += __shfl_down(vp, off, 64);
  }
  if (l == 0) { redS[w] = vs; redC[w] = vc; redP[w] = vp; }
  __syncthreads();
  if (t == 0) {
    float ts = redS[0] + redS[1] + redS[2] + redS[3];
    float tc = redC[0] + redC[1] + redC[2] + redC[3];
    unsigned tp = redP[0] + redP[1] + redP[2] + redP[3];
    if (tp) atomicAdd(&npos[b], tp);
    if (ts != 0.f) atomicAdd(&sl1sum[b], ts);
    if (tc != 0.f) atomicAdd(&cepos[b], tc);
  }
}

// ---------------- K_select: force-fixup prologue + 3-level radix + exact-T sum ----------------
__global__ __launch_bounds__(1024) void k_select(
    const float* __restrict__ loc, const float* __restrict__ conf,
    const float* __restrict__ priors, const float* __restrict__ gtb,
    const int* __restrict__ gtl, const unsigned long long* __restrict__ gtc,
    unsigned* __restrict__ key, const unsigned* __restrict__ histg,
    unsigned* __restrict__ npos, float* __restrict__ sl1sum,
    float* __restrict__ cepos, float* __restrict__ negsum,
    unsigned* __restrict__ final_tk, float* __restrict__ out) {
  __shared__ unsigned hc[NBIN];
  __shared__ unsigned h0s[H0BIN];
  __shared__ unsigned pcs[256], sc[256];
  __shared__ int wA; __shared__ unsigned kexA;
  __shared__ unsigned kS, prefS;
  __shared__ float redf[16];
  __shared__ unsigned pw16[NGT]; __shared__ float lse16[NGT], bov16[NGT];
  __shared__ int bidx16[NGT];
  int b = blockIdx.x, t = threadIdx.x;
  // ---- load lvl0 hist into LDS; precompute per-gt winner data ----
  if (t < H0BIN) h0s[t] = histg[b * H0BIN + t];
  if (t < NGT) {
    unsigned long long c64 = gtc[b * NGT + t];
    unsigned p = 0xFFFFFFFFu - (unsigned)(c64 & 0xFFFFFFFFull);
    pw16[t] = p;
    const float* row = conf + ((size_t)b * NPRI + p) * NCLS;
    float s = 0.f;
    for (int j = 0; j < NCLS; j++) s += __expf(row[j]);
    lse16[t] = __logf(s);
    f32x4 pv = ((const f32x4*)priors)[p];
    float px1 = pv[0] - 0.5f * pv[2], py1 = pv[1] - 0.5f * pv[3];
    float px2 = pv[0] + 0.5f * pv[2], py2 = pv[1] + 0.5f * pv[3];
    float parea = (px2 - px1) * (py2 - py1);
    float bov = 0.f; int g = 0;
    for (int gg = 0; gg < NGT; gg++) {   // same math as k_conf
      const f32x4 gv = ((const f32x4*)gtb)[b * NGT + gg];
      float ix = fmaxf(fminf(px2, gv[2]) - fmaxf(px1, gv[0]), 0.f);
      float iy = fmaxf(fminf(py2, gv[3]) - fmaxf(py1, gv[1]), 0.f);
      float inter = ix * iy;
      float garea = (gv[2] - gv[0]) * (gv[3] - gv[1]);
      float iou = inter / (parea + garea - inter);
      if (iou > bov) { bov = iou; g = gg; }
    }
    bov16[t] = bov; bidx16[t] = g;
  }
  __syncthreads();
  // ---- serial force-match fixup (last-wins over ascending g), <=16 priors ----
  if (t == 0) {
    unsigned np = npos[b];
    float sl = sl1sum[b], cpv = cepos[b];
    for (int i = 0; i < NGT; i++) {
      unsigned p = pw16[i];
      int prev = -1;
      for (int j = 0; j < i; j++) if (pw16[j] == p) prev = j;
      float lse = lse16[i];
      const float* row = conf + ((size_t)b * NPRI + p) * NCLS;
      f32x4 pv = ((const f32x4*)priors)[p];
      f32x4 ldv = ((const f32x4*)loc)[(size_t)b * NPRI + p];
      float newce = lse - row[gtl[b * NGT + i]];
      float newsl = sl1_terms(pv, ldv, ((const f32x4*)gtb)[b * NGT + i]);
      if (prev < 0) {
        float o = bov16[i]; int gold = bidx16[i];
        int cold = (o < F_NEG_TH) ? 0 : ((o < F_POS_TH) ? -1 : gtl[b * NGT + gold]);
        if (cold == 0) {
          unsigned ko = key[(size_t)b * NPRI + p];
          h0s[ko >> 24] -= 1u; h0s[0] += 1u;
        } else if (cold > 0) {
          np -= 1; cpv -= lse - row[cold];
          sl -= sl1_terms(pv, ldv, ((const f32x4*)gtb)[b * NGT + gold]);
        }
        np += 1; cpv += newce; sl += newsl;
        key[(size_t)b * NPRI + p] = 0u;
      } else {  // re-assigned: previous fix made it pos with g=prev
        cpv -= lse - row[gtl[b * NGT + prev]];
        sl -= sl1_terms(pv, ldv, ((const f32x4*)gtb)[b * NGT + prev]);
        cpv += newce; sl += newsl;
      }
    }
    npos[b] = np; sl1sum[b] = sl; cepos[b] = cpv;
    kS = 0u; prefS = 0u; wA = -1;
  }
  __syncthreads();
  unsigned k0 = min(3u * npos[b], (unsigned)(NPRI - 1));
  const int iters = (NPRI + 1023) / 1024;
  // ---- lvl0: 256-bin hist (fixed), suffix scan ----
  if (t < 256) { unsigned v = h0s[t]; pcs[t] = v; sc[t] = v; }
  __syncthreads();
  for (int off = 1; off < 256; off <<= 1) {
    unsigned v = 0;
    if (t < 256) v = (t + off < 256) ? sc[t + off] : 0u;
    __syncthreads();
    if (t < 256) sc[t] += v;
    __syncthreads();
  }
  if (t < 256) {
    unsigned excl = sc[t] - pcs[t];
    if (k0 > 0 && excl < k0 && k0 <= excl + pcs[t]) { wA = t; kexA = excl; }
  }
  __syncthreads();
  if (t == 0 && wA >= 0) { prefS = ((unsigned)wA) << 24; kS = k0 - kexA; }
  __syncthreads();
  // ---- lvl1 [23:12] / lvl2 [11:0]: scans over near-uniform mantissa bits ----
  for (int lvl = 1; lvl <= 2; lvl++) {
    unsigned k = kS;
    int shift = (lvl == 1) ? 12 : 0;
    int lowcut = (lvl == 1) ? 24 : 12;
    for (int i = t; i < NBIN; i += 1024) hc[i] = 0u;
    if (t == 0) wA = -1;
    __syncthreads();
    unsigned pre = prefS >> lowcut;
    if (k > 0) {
      for (int n = 0; n < iters; n++) {
        int i = n * 1024 + t;
        if (i < NPRI) {
          unsigned kk = key[(size_t)b * NPRI + i];
          if ((kk >> lowcut) == pre) atomicAdd(&hc[(kk >> shift) & 0xFFFu], 1u);
        }
      }
    }
    __syncthreads();
    if (t < 256) {
      unsigned cs = 0;
#pragma unroll
      for (int u = 0; u < 16; u++) cs += hc[t * 16 + u];
      pcs[t] = cs; sc[t] = cs;
    }
    __syncthreads();
    for (int off = 1; off < 256; off <<= 1) {
      unsigned v = 0;
      if (t < 256) v = (t + off < 256) ? sc[t + off] : 0u;
      __syncthreads();
      if (t < 256) sc[t] += v;
      __syncthreads();
    }
    if (t < 256) {
      unsigned excl = sc[t] - pcs[t];
      if (k > 0 && excl < k && k <= excl + pcs[t]) { wA = t; kexA = excl; }
    }
    __syncthreads();
    if (wA >= 0 && t < 64) {
      int w = wA; unsigned exw = kexA;
      unsigned v = (t < 16) ? hc[w * 16 + t] : 0u;
      unsigned sufv = v;
#pragma unroll
      for (int off = 1; off < 16; off <<= 1) {
        unsigned x = __shfl_down(sufv, off, 64);
        if (t + off < 16) sufv += x;
      }
      unsigned excl2 = exw + (sufv - v);
      if (t < 16 && excl2 < k && k <= excl2 + v) {
        prefS |= ((unsigned)(w * 16 + t)) << shift;
        kS = k - excl2;
      }
    }
    __syncthreads();
  }
  unsigned Tu = prefS;   // exact threshold key value
  unsigned tie = kS;
  float acc = 0.f;
  if (k0 > 0) {
    for (int n = 0; n < iters; n++) {
      int i = n * 1024 + t;
      if (i < NPRI) {
        unsigned kk = key[(size_t)b * NPRI + i];
        if (kk > Tu) acc += __uint_as_float(kk);  // uint order == float order
      }
    }
  }
#pragma unroll
  for (int off = 32; off; off >>= 1) acc += __shfl_down(acc, off, 64);
  if ((t & 63) == 0) redf[t >> 6] = acc;
  __syncthreads();
  if (t == 0) {
    float tot = 0.f;
    for (int wv = 0; wv < 16; wv++) tot += redf[wv];
    if (k0 > 0) tot += (float)tie * __uint_as_float(Tu);
    negsum[b] = tot;
    __threadfence();                       // covers fixup + negsum writes
    unsigned r2 = atomicAdd(final_tk, 1u);
    if (r2 == BATCH - 1) {                 // globally-last block combines
      __threadfence();
      float lb = 0.f, ctot = 0.f; unsigned tp = 0;
      for (int bb = 0; bb < BATCH; bb++) {
        unsigned nb = aload_u32(&npos[bb]);
        lb += aload_f32(&sl1sum[bb]) / fmaxf((float)nb, 1.f);
        tp += nb;
        ctot += aload_f32(&cepos[bb]) + aload_f32(&negsum[bb]);
      }
      out[0] = (1.5f * lb + ctot / fmaxf((float)tp, 1.f)) / (float)BATCH;
      *final_tk = 0;                       // self-clean for next replay
    }
  }
}

extern "C" void kernel_launch(void* const* d_in, const int* in_sizes, int n_in,
                              void* d_out, int out_size, void* d_ws, size_t ws_size,
                              hipStream_t stream) {
  const float* loc = (const float*)d_in[0];
  const float* conf = (const float*)d_in[1];
  const float* priors = (const float*)d_in[2];
  const float* gtb = (const float*)d_in[3];
  const int* gtl = (const int*)d_in[4];
  char* ws = (char*)d_ws;
  unsigned* key = (unsigned*)(ws + OFF_KEY);
  unsigned long long* gtc = (unsigned long long*)(ws + OFF_GTC);
  unsigned* histg = (unsigned*)(ws + OFF_HG);
  unsigned* npos = (unsigned*)(ws + OFF_NPOS);
  float* sl1sum = (float*)(ws + OFF_SL1);
  float* cepos = (float*)(ws + OFF_CEP);
  float* negsum = (float*)(ws + OFF_NEG);
  unsigned* final_tk = (unsigned*)(ws + OFF_FTK);
  float* out = (float*)d_out;

  k_init<<<1, 512, 0, stream>>>(histg, gtc);
  dim3 gridC(CBLK, BATCH);
  k_conf<<<gridC, 256, 0, stream>>>(loc, conf, priors, gtb, gtl,
                                    key, histg, gtc, npos, sl1sum, cepos);
  k_select<<<BATCH, 1024, 0, stream>>>(loc, conf, priors, gtb, gtl, gtc,
                                       key, histg, npos, sl1sum, cepos,
                                       negsum, final_tk, out);
}

// Round 18
// 159.433 us; speedup vs baseline: 1.3682x; 1.3682x over previous
//
#include <hip/hip_runtime.h>
#include <stdint.h>

#define BATCH 8
#define NPRI 100000
#define NGT 16
#define NCLS 41
#define F_POS_TH 0.5f
#define F_NEG_TH 0.4f

// k_conf geometry: 1-wave blocks, 64-row tiles, barrier-free gll pipeline
static constexpr int WTPB = 64;                        // threads per block (1 wave)
static constexpr int CPT = WTPB * NCLS / 4;            // 656 float4 chunks per tile
static constexpr int BLK_PER_B = 224;                  // persistent blocks per batch
static constexpr int TILES_PER_B = (NPRI + WTPB - 1) / WTPB; // 1563
static constexpr int H0BIN = 256;                      // lvl0 hist bins (key top-8 bits)
static constexpr int NBIN = 4096;                      // k_select lvl1/2 bins

// ---- workspace layout (bytes) ----
static constexpr size_t OFF_KEY  = 0;                               // u32 [B*P] lc bits
static constexpr size_t OFF_GTC  = OFF_KEY + (size_t)BATCH*NPRI*4;  // u64 [B*16]
static constexpr size_t OFF_HG   = OFF_GTC + BATCH*NGT*8;           // u32 [B][256] lvl0 hist
static constexpr size_t OFF_NPOS = OFF_HG + (size_t)BATCH*H0BIN*4;  // u32 [B]
static constexpr size_t OFF_SL1  = OFF_NPOS + BATCH*4;              // f32 [B]
static constexpr size_t OFF_CEP  = OFF_SL1  + BATCH*4;              // f32 [B]
static constexpr size_t OFF_NEG  = OFF_CEP  + BATCH*4;              // f32 [B]
static constexpr size_t OFF_FTK  = OFF_NEG  + BATCH*4;              // u32 [1]
static constexpr int ZERO_U32 = (int)((OFF_FTK + 4 - OFF_HG) / 4);  // hist + scalars

typedef float f32x4 __attribute__((ext_vector_type(4)));

__device__ inline float smoothl1(float d) {
  float a = fabsf(d);
  return a < 1.f ? 0.5f * d * d : a - 0.5f;
}
__device__ inline float sl1_terms(f32x4 pv, f32x4 ld, f32x4 gv) {
  float tx = ((gv[0] + gv[2]) * 0.5f - pv[0]) / (0.1f * pv[2]);
  float ty = ((gv[1] + gv[3]) * 0.5f - pv[1]) / (0.1f * pv[3]);
  float tw = __logf(fmaxf((gv[2] - gv[0]) / pv[2], 1e-8f)) / 0.2f;
  float th = __logf(fmaxf((gv[3] - gv[1]) / pv[3], 1e-8f)) / 0.2f;
  return smoothl1(ld[0] - tx) + smoothl1(ld[1] - ty)
       + smoothl1(ld[2] - tw) + smoothl1(ld[3] - th);
}
__device__ inline float aload_f32(const float* p) {
  return __hip_atomic_load(p, __ATOMIC_RELAXED, __HIP_MEMORY_SCOPE_AGENT);
}
__device__ inline unsigned aload_u32(const unsigned* p) {
  return __hip_atomic_load(p, __ATOMIC_RELAXED, __HIP_MEMORY_SCOPE_AGENT);
}
// async global->LDS, 16B per lane; LDS dest = wave-uniform base + lane*16.
__device__ __forceinline__ void gll16(const void* gsrc, void* ldst) {
  __builtin_amdgcn_global_load_lds(
      (const __attribute__((address_space(1))) void*)gsrc,
      (__attribute__((address_space(3))) void*)ldst, 16, 0, 0);
}

// ---------------- K_init: zero hist+scalars, gtc baseline ----------------
// gtc re-based every call: ws poison 0xAA.. would win atomicMax otherwise.
__global__ void k_init(unsigned* __restrict__ z, unsigned long long* __restrict__ gtc) {
  int t = threadIdx.x;  // 512 threads
  for (int i = t; i < ZERO_U32; i += 512) z[i] = 0u;
  if (t < BATCH * NGT) gtc[t] = 0xFFFFFFFFull;  // (iou=0)<<32 | (0xFFFFFFFF - p=0)
}

// ---------------- K_conf: gll pipeline + fused per-gt argmax (no force here) ----------------
// Byte-identical to round 16 (107 us, best stable variant). Keys/npos/sl1/cepos
// computed WITHOUT force-match; k_select's prologue applies the fixup.
__global__ __launch_bounds__(WTPB) void k_conf(
    const float* __restrict__ loc, const float* __restrict__ conf,
    const float* __restrict__ priors, const float* __restrict__ gtb,
    const int* __restrict__ gtl,
    unsigned* __restrict__ key, unsigned* __restrict__ histg,
    unsigned long long* __restrict__ gtc,
    unsigned* __restrict__ npos, float* __restrict__ sl1sum, float* __restrict__ cepos) {
  __shared__ float buf[2][CPT * 4];      // 2 x 10496 B
  __shared__ unsigned hcb[H0BIN];        // 1 KB lvl0 hist
  __shared__ unsigned long long best[NGT];
  int t = threadIdx.x;
  int b = blockIdx.x / BLK_PER_B;
  int sub = blockIdx.x % BLK_PER_B;
  const f32x4* conf4 = (const f32x4*)conf;
  const size_t bbase4 = (size_t)b * NPRI * NCLS / 4;
  const size_t maxc4 = (size_t)BATCH * NPRI * NCLS / 4 - 1;
  float acc_s = 0.f, acc_c = 0.f; unsigned acc_p = 0;
#pragma unroll
  for (int u = 0; u < H0BIN / WTPB; u++) hcb[t + u * WTPB] = 0u;  // 1 wave: in-order
  if (t < NGT) best[t] = 0;

  // prologue: stage first tile into buf[0] (10 full glls + 1 partial)
  {
    size_t base4 = bbase4 + (size_t)sub * CPT;
#pragma unroll
    for (int u = 0; u < 10; u++) {
      size_t g4 = base4 + (unsigned)(t + u * WTPB);
      if (g4 > maxc4) g4 = maxc4;
      gll16(conf4 + g4, &buf[0][(t + u * WTPB) * 4]);
    }
    if (t < CPT - 10 * WTPB) {
      size_t g4 = base4 + (unsigned)(t + 10 * WTPB);
      if (g4 > maxc4) g4 = maxc4;
      gll16(conf4 + g4, &buf[0][(t + 10 * WTPB) * 4]);
    }
  }
  int cur = 0;
  for (int tidx = sub; tidx < TILES_PER_B; tidx += BLK_PER_B) {
    int p = tidx * WTPB + t;
    bool valid = p < NPRI;
    int pc = valid ? p : NPRI - 1;
    f32x4 pv = ((const f32x4*)priors)[pc];
    f32x4 ld = ((const f32x4*)loc)[(size_t)b * NPRI + pc];
    int nxt = tidx + BLK_PER_B;
    if (nxt < TILES_PER_B) {
      size_t base4 = bbase4 + (size_t)nxt * CPT;
#pragma unroll
      for (int u = 0; u < 10; u++) {
        size_t g4 = base4 + (unsigned)(t + u * WTPB);
        if (g4 > maxc4) g4 = maxc4;
        gll16(conf4 + g4, &buf[cur ^ 1][(t + u * WTPB) * 4]);
      }
      if (t < CPT - 10 * WTPB) {
        size_t g4 = base4 + (unsigned)(t + 10 * WTPB);
        if (g4 > maxc4) g4 = maxc4;
        gll16(conf4 + g4, &buf[cur ^ 1][(t + 10 * WTPB) * 4]);
      }
      __builtin_amdgcn_sched_barrier(0);
      asm volatile("s_waitcnt vmcnt(11)");
      __builtin_amdgcn_sched_barrier(0);
    } else {
      __builtin_amdgcn_sched_barrier(0);
      asm volatile("s_waitcnt vmcnt(0)");
      __builtin_amdgcn_sched_barrier(0);
    }
    // ---- compute tile i from buf[cur] (single wave) ----
    unsigned kkreg = 0u;
    if (valid) {
      float px1 = pv[0] - 0.5f * pv[2], py1 = pv[1] - 0.5f * pv[3];
      float px2 = pv[0] + 0.5f * pv[2], py2 = pv[1] + 0.5f * pv[3];
      float parea = (px2 - px1) * (py2 - py1);
      float bov = 0.f; int g = 0;
#pragma unroll
      for (int gg = 0; gg < NGT; gg++) {
        const f32x4 gv = ((const f32x4*)gtb)[b * NGT + gg];
        float ix = fmaxf(fminf(px2, gv[2]) - fmaxf(px1, gv[0]), 0.f);
        float iy = fmaxf(fminf(py2, gv[3]) - fmaxf(py1, gv[1]), 0.f);
        float inter = ix * iy;
        float garea = (gv[2] - gv[0]) * (gv[3] - gv[1]);
        float iou = inter / (parea + garea - inter);
        if (iou > bov) { bov = iou; g = gg; }
        if (iou > 0.f) {                 // fused per-gt argmax
          unsigned long long comp = ((unsigned long long)__float_as_uint(iou) << 32)
                                  | (unsigned long long)(0xFFFFFFFFu - (unsigned)p);
          if (comp > best[gg]) atomicMax(&best[gg], comp);
        }
      }
      int c = gtl[b * NGT + g];
      if (bov < F_POS_TH) c = -1;
      if (bov < F_NEG_TH) c = 0;
      const float* r = &buf[cur][t * NCLS];  // stride 41 floats
      float s = 0.f, r0 = 0.f, rc = 0.f;
#pragma unroll
      for (int j = 0; j < NCLS; j++) {       // |x|<~7: direct exp-sum safe in f32
        float v = r[j];
        s += __expf(v);
        if (j == 0) r0 = v;
        if (j == c) rc = v;
      }
      float lse = __logf(s);
      kkreg = (c == 0) ? __float_as_uint(lse - r0) : 0u;
      key[(size_t)b * NPRI + p] = kkreg;
      if (c > 0) {
        acc_p += 1;
        acc_c += lse - rc;
        const f32x4 gvb = ((const f32x4*)gtb)[b * NGT + g];
        acc_s += sl1_terms(pv, ld, gvb);
      }
    }
    // lvl0 hist, hot bins (0x40 and 0) ballot-aggregated
    unsigned bin = kkreg >> 24;
    unsigned long long m40 = __ballot(valid && kkreg != 0u && bin == 0x40u);
    unsigned long long m00 = __ballot(valid && kkreg == 0u);
    if (m40 && t == __ffsll((long long)m40) - 1)
      atomicAdd(&hcb[0x40], (unsigned)__popcll(m40));
    if (m00 && t == __ffsll((long long)m00) - 1)
      atomicAdd(&hcb[0], (unsigned)__popcll(m00));
    if (valid && kkreg != 0u && bin != 0x40u) atomicAdd(&hcb[bin], 1u);
    cur ^= 1;
  }
  // flush: per-gt candidates + hist (same wave: ds ops already ordered)
  if (t < NGT && best[t] != 0) atomicMax(&gtc[b * NGT + t], best[t]);
#pragma unroll
  for (int u = 0; u < H0BIN / WTPB; u++) {
    unsigned v = hcb[t + u * WTPB];
    if (v) atomicAdd(&histg[b * H0BIN + t + u * WTPB], v);
  }
  float vs = acc_s, vc = acc_c; unsigned vp = acc_p;
#pragma unroll
  for (int off = 32; off; off >>= 1) {
    vs += __shfl_down(vs, off, 64);
    vc += __shfl_down(vc, off, 64);
    vp += __shfl_down(vp, off, 64);
  }
  if (t == 0) {
    if (vp) atomicAdd(&npos[b], vp);
    if (vs != 0.f) atomicAdd(&sl1sum[b], vs);
    if (vc != 0.f) atomicAdd(&cepos[b], vc);
  }
}

// ---------------- K_select: PARALLEL force-fixup + 3-level radix + exact-T sum ----------------
// Fixup parallelized across 16 lanes: per gt i, is_first = no j<i with same
// winner-prior, is_last = no j>i. Net serial-loop effect == (is_first: undo old
// contribution, np++) + (is_last: add new contribution with gt i). All global
// reads/log chains run concurrently; combine via wave reduce.
__global__ __launch_bounds__(1024) void k_select(
    const float* __restrict__ loc, const float* __restrict__ conf,
    const float* __restrict__ priors, const float* __restrict__ gtb,
    const int* __restrict__ gtl, const unsigned long long* __restrict__ gtc,
    unsigned* __restrict__ key, const unsigned* __restrict__ histg,
    unsigned* __restrict__ npos, float* __restrict__ sl1sum,
    float* __restrict__ cepos, float* __restrict__ negsum,
    unsigned* __restrict__ final_tk, float* __restrict__ out) {
  __shared__ unsigned hc[NBIN];
  __shared__ unsigned h0s[H0BIN];
  __shared__ unsigned pcs[256], sc[256];
  __shared__ int wA; __shared__ unsigned kexA;
  __shared__ unsigned kS, prefS;
  __shared__ float redf[16];
  __shared__ unsigned pw16[NGT];
  int b = blockIdx.x, t = threadIdx.x;
  if (t < H0BIN) h0s[t] = histg[b * H0BIN + t];
  if (t < NGT)
    pw16[t] = 0xFFFFFFFFu - (unsigned)(gtc[b * NGT + t] & 0xFFFFFFFFull);
  if (t == 0) { kS = 0u; prefS = 0u; wA = -1; }
  __syncthreads();
  // ---- parallel fixup (lanes 0..15 of wave 0 carry work; others contribute 0) ----
  float d_sl = 0.f, d_ce = 0.f; int d_np = 0;
  if (t < NGT) {
    unsigned p = pw16[t];
    bool is_first = true, is_last = true;
    for (int j = 0; j < NGT; j++) {
      if (j < t && pw16[j] == p) is_first = false;
      if (j > t && pw16[j] == p) is_last = false;
    }
    const float* row = conf + ((size_t)b * NPRI + p) * NCLS;
    float s = 0.f;
    for (int j = 0; j < NCLS; j++) s += __expf(row[j]);
    float lse = __logf(s);
    f32x4 pv = ((const f32x4*)priors)[p];
    f32x4 ldv = ((const f32x4*)loc)[(size_t)b * NPRI + p];
    if (is_first) {
      // recompute original match of prior p (same math as k_conf)
      float px1 = pv[0] - 0.5f * pv[2], py1 = pv[1] - 0.5f * pv[3];
      float px2 = pv[0] + 0.5f * pv[2], py2 = pv[1] + 0.5f * pv[3];
      float parea = (px2 - px1) * (py2 - py1);
      float bov = 0.f; int gold = 0;
      for (int gg = 0; gg < NGT; gg++) {
        const f32x4 gv = ((const f32x4*)gtb)[b * NGT + gg];
        float ix = fmaxf(fminf(px2, gv[2]) - fmaxf(px1, gv[0]), 0.f);
        float iy = fmaxf(fminf(py2, gv[3]) - fmaxf(py1, gv[1]), 0.f);
        float inter = ix * iy;
        float garea = (gv[2] - gv[0]) * (gv[3] - gv[1]);
        float iou = inter / (parea + garea - inter);
        if (iou > bov) { bov = iou; gold = gg; }
      }
      int cold = (bov < F_NEG_TH) ? 0 : ((bov < F_POS_TH) ? -1 : gtl[b * NGT + gold]);
      if (cold == 0) {          // was background: move its hist count to bin 0
        unsigned ko = key[(size_t)b * NPRI + p];
        atomicSub(&h0s[ko >> 24], 1u);
        atomicAdd(&h0s[0], 1u);
      } else if (cold > 0) {    // was positive with gold: undo
        d_np -= 1;
        d_ce -= lse - row[cold];
        d_sl -= sl1_terms(pv, ldv, ((const f32x4*)gtb)[b * NGT + gold]);
      }
      d_np += 1;
      key[(size_t)b * NPRI + p] = 0u;  // idempotent across duplicates
    }
    if (is_last) {              // final assignment: gt = t (last-wins)
      d_ce += lse - row[gtl[b * NGT + t]];
      d_sl += sl1_terms(pv, ldv, ((const f32x4*)gtb)[b * NGT + t]);
    }
  }
  if (t < 64) {                 // wave 0 reduce (lanes >=16 carry zeros)
    float vs = d_sl, vc = d_ce; int vp = d_np;
#pragma unroll
    for (int off = 32; off; off >>= 1) {
      vs += __shfl_down(vs, off, 64);
      vc += __shfl_down(vc, off, 64);
      vp += __shfl_down(vp, off, 64);
    }
    if (t == 0) {
      npos[b] = (unsigned)((int)npos[b] + vp);
      sl1sum[b] += vs;
      cepos[b] += vc;
    }
  }
  __syncthreads();
  unsigned k0 = min(3u * npos[b], (unsigned)(NPRI - 1));
  const int iters = (NPRI + 1023) / 1024;
  // ---- lvl0: 256-bin hist (fixed), suffix scan ----
  if (t < 256) { unsigned v = h0s[t]; pcs[t] = v; sc[t] = v; }
  __syncthreads();
  for (int off = 1; off < 256; off <<= 1) {
    unsigned v = 0;
    if (t < 256) v = (t + off < 256) ? sc[t + off] : 0u;
    __syncthreads();
    if (t < 256) sc[t] += v;
    __syncthreads();
  }
  if (t < 256) {
    unsigned excl = sc[t] - pcs[t];
    if (k0 > 0 && excl < k0 && k0 <= excl + pcs[t]) { wA = t; kexA = excl; }
  }
  __syncthreads();
  if (t == 0 && wA >= 0) { prefS = ((unsigned)wA) << 24; kS = k0 - kexA; }
  __syncthreads();
  // ---- lvl1 [23:12] / lvl2 [11:0]: scans over near-uniform mantissa bits ----
  for (int lvl = 1; lvl <= 2; lvl++) {
    unsigned k = kS;
    int shift = (lvl == 1) ? 12 : 0;
    int lowcut = (lvl == 1) ? 24 : 12;
    for (int i = t; i < NBIN; i += 1024) hc[i] = 0u;
    if (t == 0) wA = -1;
    __syncthreads();
    unsigned pre = prefS >> lowcut;
    if (k > 0) {
      for (int n = 0; n < iters; n++) {
        int i = n * 1024 + t;
        if (i < NPRI) {
          unsigned kk = key[(size_t)b * NPRI + i];
          if ((kk >> lowcut) == pre) atomicAdd(&hc[(kk >> shift) & 0xFFFu], 1u);
        }
      }
    }
    __syncthreads();
    if (t < 256) {
      unsigned cs = 0;
#pragma unroll
      for (int u = 0; u < 16; u++) cs += hc[t * 16 + u];
      pcs[t] = cs; sc[t] = cs;
    }
    __syncthreads();
    for (int off = 1; off < 256; off <<= 1) {
      unsigned v = 0;
      if (t < 256) v = (t + off < 256) ? sc[t + off] : 0u;
      __syncthreads();
      if (t < 256) sc[t] += v;
      __syncthreads();
    }
    if (t < 256) {
      unsigned excl = sc[t] - pcs[t];
      if (k > 0 && excl < k && k <= excl + pcs[t]) { wA = t; kexA = excl; }
    }
    __syncthreads();
    if (wA >= 0 && t < 64) {
      int w = wA; unsigned exw = kexA;
      unsigned v = (t < 16) ? hc[w * 16 + t] : 0u;
      unsigned sufv = v;
#pragma unroll
      for (int off = 1; off < 16; off <<= 1) {
        unsigned x = __shfl_down(sufv, off, 64);
        if (t + off < 16) sufv += x;
      }
      unsigned excl2 = exw + (sufv - v);
      if (t < 16 && excl2 < k && k <= excl2 + v) {
        prefS |= ((unsigned)(w * 16 + t)) << shift;
        kS = k - excl2;
      }
    }
    __syncthreads();
  }
  unsigned Tu = prefS;   // exact threshold key value
  unsigned tie = kS;
  float acc = 0.f;
  if (k0 > 0) {
    for (int n = 0; n < iters; n++) {
      int i = n * 1024 + t;
      if (i < NPRI) {
        unsigned kk = key[(size_t)b * NPRI + i];
        if (kk > Tu) acc += __uint_as_float(kk);  // uint order == float order
      }
    }
  }
#pragma unroll
  for (int off = 32; off; off >>= 1) acc += __shfl_down(acc, off, 64);
  if ((t & 63) == 0) redf[t >> 6] = acc;
  __syncthreads();
  if (t == 0) {
    float tot = 0.f;
    for (int wv = 0; wv < 16; wv++) tot += redf[wv];
    if (k0 > 0) tot += (float)tie * __uint_as_float(Tu);
    negsum[b] = tot;
    __threadfence();                       // covers fixup + negsum writes
    unsigned r2 = atomicAdd(final_tk, 1u);
    if (r2 == BATCH - 1) {                 // globally-last block combines
      __threadfence();
      float lb = 0.f, ctot = 0.f; unsigned tp = 0;
      for (int bb = 0; bb < BATCH; bb++) {
        unsigned nb = aload_u32(&npos[bb]);
        lb += aload_f32(&sl1sum[bb]) / fmaxf((float)nb, 1.f);
        tp += nb;
        ctot += aload_f32(&cepos[bb]) + aload_f32(&negsum[bb]);
      }
      out[0] = (1.5f * lb + ctot / fmaxf((float)tp, 1.f)) / (float)BATCH;
      *final_tk = 0;                       // self-clean for next replay
    }
  }
}

extern "C" void kernel_launch(void* const* d_in, const int* in_sizes, int n_in,
                              void* d_out, int out_size, void* d_ws, size_t ws_size,
                              hipStream_t stream) {
  const float* loc = (const float*)d_in[0];
  const float* conf = (const float*)d_in[1];
  const float* priors = (const float*)d_in[2];
  const float* gtb = (const float*)d_in[3];
  const int* gtl = (const int*)d_in[4];
  char* ws = (char*)d_ws;
  unsigned* key = (unsigned*)(ws + OFF_KEY);
  unsigned long long* gtc = (unsigned long long*)(ws + OFF_GTC);
  unsigned* histg = (unsigned*)(ws + OFF_HG);
  unsigned* npos = (unsigned*)(ws + OFF_NPOS);
  float* sl1sum = (float*)(ws + OFF_SL1);
  float* cepos = (float*)(ws + OFF_CEP);
  float* negsum = (float*)(ws + OFF_NEG);
  unsigned* final_tk = (unsigned*)(ws + OFF_FTK);
  float* out = (float*)d_out;

  k_init<<<1, 512, 0, stream>>>(histg, gtc);
  k_conf<<<BATCH * BLK_PER_B, WTPB, 0, stream>>>(loc, conf, priors, gtb, gtl,
                                                 key, histg, gtc, npos, sl1sum, cepos);
  k_select<<<BATCH, 1024, 0, stream>>>(loc, conf, priors, gtb, gtl, gtc,
                                       key, histg, npos, sl1sum, cepos,
                                       negsum, final_tk, out);
}